// Round 1
// 993.966 us; speedup vs baseline: 1.1455x; 1.1455x over previous
//
#include <hip/hip_runtime.h>

typedef unsigned short u16;
typedef __bf16 bf16x8 __attribute__((ext_vector_type(8)));
typedef float f32x4 __attribute__((ext_vector_type(4)));

union BF8 {
    bf16x8 v;
    __bf16 e[8];
    u16 h[8];
};

typedef __attribute__((address_space(1))) void gvoid;
typedef __attribute__((address_space(3))) void lvoid;

__device__ __forceinline__ u16 f2bf(float f) {
    __bf16 h = (__bf16)f;
    return __builtin_bit_cast(u16, h);
}

// async global->LDS, 16B per lane; LDS dest must be wave-uniform base + lane*16
__device__ __forceinline__ void gld_lds16(const void* g, void* l) {
    __builtin_amdgcn_global_load_lds((gvoid*)g, (lvoid*)l, 16, 0, 0);
}

__device__ __forceinline__ f32x4 mfma16(bf16x8 a, bf16x8 b, f32x4 c) {
    return __builtin_amdgcn_mfma_f32_16x16x32_bf16(a, b, c, 0, 0, 0);
}

// ---------------------------------------------------------------------------
// Transpose 768x768 f32 -> bf16 (dst[n][k] = src[k][n])
// ---------------------------------------------------------------------------
__global__ __launch_bounds__(256) void transpose_cvt(const float* __restrict__ src,
                                                     u16* __restrict__ dst) {
    __shared__ float t[64][65];
    const int c0 = blockIdx.x * 64, r0 = blockIdx.y * 64;
    const int tid = threadIdx.x;
#pragma unroll
    for (int i = 0; i < 16; ++i) {
        int e = tid + 256 * i;
        int rr = e >> 6, cc = e & 63;
        t[rr][cc] = src[(r0 + rr) * 768 + c0 + cc];
    }
    __syncthreads();
#pragma unroll
    for (int i = 0; i < 16; ++i) {
        int e = tid + 256 * i;
        int rr = e >> 6, cc = e & 63;
        dst[(c0 + rr) * 768 + r0 + cc] = f2bf(t[cc][rr]);
    }
}

// ---------------------------------------------------------------------------
// GEMM: Out[M=65536][768] = A[65536][768] * Bt^T + bias  (Bt is [N][K] bf16)
// 128x128 tile, BK=32, 256 threads. XOR-swizzled LDS (bank-conflict-free b128
// fragment reads, compatible with global_load_lds contiguous-dest rule).
//
// XCD-aware block mapping (T1): bid = xcd + 8*local (consecutive bids
// round-robin the 8 XCDs). All J n-blocks of one 128-row A panel get the SAME
// xcd and consecutive local slots, so the A panel is fetched into exactly one
// XCD's L2 (grid sizes are multiples of 8 -> bijective).
//   local = bid>>3;  j = local % J;  m-panel = (bid&7)*64 + local/J
//
// FUSE: J=12, n-blocks 0..5 use {Bt0,bias0,Out0}, 6..11 use {Bt1,bias1,Out1}
// (fused K+V projection: the shared A = `values` is streamed from HBM once).
// ---------------------------------------------------------------------------
template <bool A_F32, bool OUT_F32, bool FUSE>
__global__ __launch_bounds__(256) void gemm_kernel(
    const void* __restrict__ Aptr,
    const u16* __restrict__ Bt0, const float* __restrict__ bias0, void* __restrict__ Out0,
    const u16* __restrict__ Bt1, const float* __restrict__ bias1, void* __restrict__ Out1) {
    constexpr int ASMEM = A_F32 ? 16384 : 8192;
    constexpr int J = FUSE ? 12 : 6;
    __shared__ __attribute__((aligned(16))) char smem[ASMEM + 8192];
    float* Asf = (float*)smem;
    u16* Asb = (u16*)smem;
    u16* Bs = (u16*)(smem + ASMEM);

    const int bid = blockIdx.x;
    const int xcd = bid & 7;
    const int local = bid >> 3;
    const int j = local % J;
    const int mp = xcd * 64 + local / J;

    const bool first = !FUSE || (j < 6);
    const u16* Bt = first ? Bt0 : Bt1;
    const float* bias = first ? bias0 : bias1;
    void* Out = first ? Out0 : Out1;

    const int tid = threadIdx.x;
    const int wid = tid >> 6, lane = tid & 63;
    const int quad = lane >> 4, lm = lane & 15;
    const int mbase = (wid >> 1) * 64, nbase = (wid & 1) * 64;
    const long row0 = (long)mp * 128;
    const int n0 = (FUSE ? (j % 6) : j) * 128;

    const f32x4 zero = {0.f, 0.f, 0.f, 0.f};
    f32x4 acc[4][4];
#pragma unroll
    for (int mi = 0; mi < 4; ++mi)
#pragma unroll
        for (int ni = 0; ni < 4; ++ni) acc[mi][ni] = zero;

    for (int kt = 0; kt < 24; ++kt) {
        const int k0 = kt * 32;
        if constexpr (A_F32) {
            const float* A = (const float*)Aptr;
#pragma unroll
            for (int i = 0; i < 4; ++i) {
                int chunk = tid + 256 * i;  // 1024 chunks of 16B = 128x32 f32
                int m = chunk >> 3, s = chunk & 7;
                int kc = s ^ (m & 7);  // swizzled source column-chunk
                gld_lds16(A + (row0 + m) * 768 + k0 + kc * 4, Asf + chunk * 4);
            }
        } else {
            const u16* A = (const u16*)Aptr;
#pragma unroll
            for (int i = 0; i < 2; ++i) {
                int chunk = tid + 256 * i;  // 512 chunks = 128x32 bf16
                int m = chunk >> 2, s = chunk & 3;
                int kc = s ^ ((m >> 1) & 3);
                gld_lds16(A + (row0 + m) * 768 + k0 + kc * 8, Asb + chunk * 8);
            }
        }
#pragma unroll
        for (int i = 0; i < 2; ++i) {
            int chunk = tid + 256 * i;  // 512 chunks = 128(n) x 32(k) bf16
            int n = chunk >> 2, s = chunk & 3;
            int kc = s ^ ((n >> 1) & 3);
            gld_lds16(Bt + (long)(n0 + n) * 768 + k0 + kc * 8, Bs + chunk * 8);
        }
        __syncthreads();

        bf16x8 af[4], bfr[4];
#pragma unroll
        for (int mi = 0; mi < 4; ++mi) {
            int m = mbase + mi * 16 + lm;
            if constexpr (A_F32) {
                int c0 = m * 8 + ((quad * 2) ^ (m & 7));
                int c1 = m * 8 + ((quad * 2 + 1) ^ (m & 7));
                f32x4 x0 = *(const f32x4*)(Asf + c0 * 4);
                f32x4 x1 = *(const f32x4*)(Asf + c1 * 4);
                BF8 u;
#pragma unroll
                for (int jj = 0; jj < 4; ++jj) {
                    u.e[jj] = (__bf16)x0[jj];
                    u.e[4 + jj] = (__bf16)x1[jj];
                }
                af[mi] = u.v;
            } else {
                int c = m * 4 + (quad ^ ((m >> 1) & 3));
                af[mi] = *(const bf16x8*)(Asb + c * 8);
            }
        }
#pragma unroll
        for (int ni = 0; ni < 4; ++ni) {
            int n = nbase + ni * 16 + lm;
            int c = n * 4 + (quad ^ ((n >> 1) & 3));
            bfr[ni] = *(const bf16x8*)(Bs + c * 8);
        }
#pragma unroll
        for (int mi = 0; mi < 4; ++mi)
#pragma unroll
            for (int ni = 0; ni < 4; ++ni)
                acc[mi][ni] = mfma16(af[mi], bfr[ni], acc[mi][ni]);
        __syncthreads();
    }

    // epilogue: C/D layout row = quad*4+r, col = lane&15
#pragma unroll
    for (int mi = 0; mi < 4; ++mi) {
        const long row = row0 + mbase + mi * 16 + quad * 4;
#pragma unroll
        for (int ni = 0; ni < 4; ++ni) {
            const int n = n0 + nbase + ni * 16 + lm;
            const float bv = bias[n];
#pragma unroll
            for (int r = 0; r < 4; ++r) {
                float v = acc[mi][ni][r] + bv;
                if constexpr (OUT_F32)
                    ((float*)Out)[(row + r) * 768 + n] = v;
                else
                    ((u16*)Out)[(row + r) * 768 + n] = f2bf(v);
            }
        }
    }
}

// ---------------------------------------------------------------------------
// Axis attention: one block per (cross-pos, batch, head). head<6: attend along
// H; head>=6: along W. Seq 64, head dim 64. Q/K/V staged swizzled; V
// transposed in LDS (padded stride 72) so PV B-fragments are single b128s.
// ---------------------------------------------------------------------------
__global__ __launch_bounds__(256) void attn_kernel(const u16* __restrict__ q,
                                                   const u16* __restrict__ k,
                                                   const u16* __restrict__ v,
                                                   u16* __restrict__ o) {
    __shared__ __attribute__((aligned(16))) u16 Qs[64 * 64];
    __shared__ __attribute__((aligned(16))) u16 Ks[64 * 64];
    __shared__ __attribute__((aligned(16))) u16 Vs[64 * 64];
    __shared__ __attribute__((aligned(16))) u16 Vt[64 * 72];  // padded stride

    const int cross = blockIdx.x;
    const int b = blockIdx.y;
    const int head = blockIdx.z;
    const bool axis0 = head < 6;
    const int tid = threadIdx.x;
    const int wid = tid >> 6, lane = tid & 63;
    const int quad = lane >> 4, lm = lane & 15;

    const long base = (long)b * 4096 + (axis0 ? cross : cross * 64);
    const int pstride = axis0 ? 64 : 1;
    const int coloff = head * 64;

    // stage Q,K,V swizzled: slot(p, c) = p*8 + (c ^ (p&7)), 16B chunks
#pragma unroll
    for (int i = 0; i < 2; ++i) {
        int chunk = tid + 256 * i;  // 512 chunks = 64 pos x 8 chunks
        int p = chunk >> 3, s = chunk & 7;
        int c = s ^ (p & 7);
        long g = (base + (long)p * pstride) * 768 + coloff + c * 8;
        gld_lds16(q + g, Qs + chunk * 8);
        gld_lds16(k + g, Ks + chunk * 8);
        gld_lds16(v + g, Vs + chunk * 8);
    }
    __syncthreads();

    // transpose V: Vs[pos][d] (swizzled) -> Vt[d][pos] (stride 72)
#pragma unroll
    for (int i = 0; i < 2; ++i) {
        int chunk = tid + 256 * i;
        int pos = chunk & 63, cc = chunk >> 6;  // cc wave-uniform
        int slot = pos * 8 + (cc ^ (pos & 7));
        BF8 vv;
        vv.v = *(const bf16x8*)(Vs + slot * 8);
#pragma unroll
        for (int jj = 0; jj < 8; ++jj) Vt[(cc * 8 + jj) * 72 + pos] = vv.h[jj];
    }

    // S = Q K^T ; wave owns rows 16*wid..16*wid+15
    const f32x4 zero = {0.f, 0.f, 0.f, 0.f};
    f32x4 s[4];
#pragma unroll
    for (int nt = 0; nt < 4; ++nt) s[nt] = zero;

    bf16x8 qf[2];
#pragma unroll
    for (int kt = 0; kt < 2; ++kt) {
        int row = 16 * wid + lm;
        int slot = row * 8 + ((kt * 4 + quad) ^ (row & 7));
        qf[kt] = *(const bf16x8*)(Qs + slot * 8);
    }
#pragma unroll
    for (int nt = 0; nt < 4; ++nt)
#pragma unroll
        for (int kt = 0; kt < 2; ++kt) {
            int row = nt * 16 + lm;
            int slot = row * 8 + ((kt * 4 + quad) ^ (row & 7));
            bf16x8 kf = *(const bf16x8*)(Ks + slot * 8);
            s[nt] = mfma16(qf[kt], kf, s[nt]);
        }

    // softmax over 64 keys (rows h = 16*wid + quad*4 + r)
    float invl[4];
#pragma unroll
    for (int nt = 0; nt < 4; ++nt) s[nt] = s[nt] * 0.125f;  // 1/sqrt(64)
#pragma unroll
    for (int r = 0; r < 4; ++r) {
        float m = fmaxf(fmaxf(s[0][r], s[1][r]), fmaxf(s[2][r], s[3][r]));
#pragma unroll
        for (int d = 1; d < 16; d <<= 1) m = fmaxf(m, __shfl_xor(m, d));
        float l = 0.f;
#pragma unroll
        for (int nt = 0; nt < 4; ++nt) {
            float p = exp2f((s[nt][r] - m) * 1.44269504f);
            s[nt][r] = p;
            l += p;
        }
#pragma unroll
        for (int d = 1; d < 16; d <<= 1) l += __shfl_xor(l, d);
        invl[r] = 1.f / l;
    }

    // P (unnormalized bf16) -> Qs, same swizzled layout; wave writes only its
    // own 16 rows (the only Qs rows it reads), so no barrier needed here.
#pragma unroll
    for (int nt = 0; nt < 4; ++nt)
#pragma unroll
        for (int r = 0; r < 4; ++r) {
            int h = 16 * wid + quad * 4 + r;
            int c = nt * 2 + (lm >> 3);
            Qs[(h * 8 + (c ^ (h & 7))) * 8 + (lm & 7)] = f2bf(s[nt][r]);
        }
    __syncthreads();  // Vt ready (all waves) + P ready

    // O = P V ; B-fragment = single b128 from Vt
    f32x4 oacc[4];
#pragma unroll
    for (int nt = 0; nt < 4; ++nt) oacc[nt] = zero;
#pragma unroll
    for (int kt = 0; kt < 2; ++kt) {
        int row = 16 * wid + lm;
        int slot = row * 8 + ((kt * 4 + quad) ^ (row & 7));
        bf16x8 pf = *(const bf16x8*)(Qs + slot * 8);
#pragma unroll
        for (int nt = 0; nt < 4; ++nt) {
            bf16x8 vf = *(const bf16x8*)(Vt + (nt * 16 + lm) * 72 + kt * 32 + quad * 8);
            oacc[nt] = mfma16(pf, vf, oacc[nt]);
        }
    }

#pragma unroll
    for (int nt = 0; nt < 4; ++nt)
#pragma unroll
        for (int r = 0; r < 4; ++r) {
            int p = 16 * wid + quad * 4 + r;
            long grow = base + (long)p * pstride;
            o[grow * 768 + coloff + nt * 16 + lm] = f2bf(oacc[nt][r] * invl[r]);
        }
}

// ---------------------------------------------------------------------------
// ws layout (u16 units): q | k | v | attn (each 65536*768) | 4 x 768*768 wts
// ---------------------------------------------------------------------------
extern "C" void kernel_launch(void* const* d_in, const int* in_sizes, int n_in,
                              void* d_out, int out_size, void* d_ws, size_t ws_size,
                              hipStream_t stream) {
    const float* queries = (const float*)d_in[0];
    const float* values = (const float*)d_in[1];
    const float* Wq = (const float*)d_in[2];
    const float* bq = (const float*)d_in[3];
    const float* Wk = (const float*)d_in[4];
    const float* bk = (const float*)d_in[5];
    const float* Wv = (const float*)d_in[6];
    const float* bv = (const float*)d_in[7];
    const float* Wo = (const float*)d_in[8];
    const float* bo = (const float*)d_in[9];

    const long MAT = 65536L * 768;
    const long WMAT = 768L * 768;
    u16* qws = (u16*)d_ws;
    u16* kws = qws + MAT;
    u16* vws = kws + MAT;
    u16* aws = vws + MAT;
    u16* wtq = aws + MAT;
    u16* wtk = wtq + WMAT;
    u16* wtv = wtk + WMAT;
    u16* wto = wtv + WMAT;

    dim3 tb(256);
    dim3 tg(12, 12);
    transpose_cvt<<<tg, tb, 0, stream>>>(Wq, wtq);
    transpose_cvt<<<tg, tb, 0, stream>>>(Wk, wtk);
    transpose_cvt<<<tg, tb, 0, stream>>>(Wv, wtv);
    transpose_cvt<<<tg, tb, 0, stream>>>(Wo, wto);

    // 512 m-panels x J n-blocks, XCD-swizzled inside the kernel (grids %8==0)
    gemm_kernel<true, false, false><<<dim3(512 * 6), tb, 0, stream>>>(
        queries, wtq, bq, qws, nullptr, nullptr, nullptr);
    gemm_kernel<true, false, true><<<dim3(512 * 12), tb, 0, stream>>>(
        values, wtk, bk, kws, wtv, bv, vws);

    attn_kernel<<<dim3(64, 16, 12), tb, 0, stream>>>(qws, kws, vws, aws);

    gemm_kernel<false, true, false><<<dim3(512 * 6), tb, 0, stream>>>(
        aws, wto, bo, (float*)d_out, nullptr, nullptr, nullptr);
}

// Round 2
// 979.176 us; speedup vs baseline: 1.1628x; 1.0151x over previous
//
#include <hip/hip_runtime.h>

typedef unsigned short u16;
typedef __bf16 bf16x8 __attribute__((ext_vector_type(8)));
typedef float f32x4 __attribute__((ext_vector_type(4)));

union BF8 {
    bf16x8 v;
    __bf16 e[8];
    u16 h[8];
};

typedef __attribute__((address_space(1))) void gvoid;
typedef __attribute__((address_space(3))) void lvoid;

__device__ __forceinline__ u16 f2bf(float f) {
    __bf16 h = (__bf16)f;
    return __builtin_bit_cast(u16, h);
}

// async global->LDS, 16B per lane; LDS dest must be wave-uniform base + lane*16
__device__ __forceinline__ void gld_lds16(const void* g, void* l) {
    __builtin_amdgcn_global_load_lds((gvoid*)g, (lvoid*)l, 16, 0, 0);
}

__device__ __forceinline__ f32x4 mfma16(bf16x8 a, bf16x8 b, f32x4 c) {
    return __builtin_amdgcn_mfma_f32_16x16x32_bf16(a, b, c, 0, 0, 0);
}

// ---------------------------------------------------------------------------
// Transpose 768x768 f32 -> bf16 (dst[n][k] = src[k][n])
// ---------------------------------------------------------------------------
__global__ __launch_bounds__(256) void transpose_cvt(const float* __restrict__ src,
                                                     u16* __restrict__ dst) {
    __shared__ float t[64][65];
    const int c0 = blockIdx.x * 64, r0 = blockIdx.y * 64;
    const int tid = threadIdx.x;
#pragma unroll
    for (int i = 0; i < 16; ++i) {
        int e = tid + 256 * i;
        int rr = e >> 6, cc = e & 63;
        t[rr][cc] = src[(r0 + rr) * 768 + c0 + cc];
    }
    __syncthreads();
#pragma unroll
    for (int i = 0; i < 16; ++i) {
        int e = tid + 256 * i;
        int rr = e >> 6, cc = e & 63;
        dst[(c0 + rr) * 768 + r0 + cc] = f2bf(t[cc][rr]);
    }
}

// ---------------------------------------------------------------------------
// Elementwise f32 -> bf16 (vectorized, 8 elems/thread). Used to pre-convert
// `values` so the fused KV GEMM runs the bf16-A path (half staging bytes,
// no in-loop cvt, double-buffered LDS fits).
// ---------------------------------------------------------------------------
__global__ __launch_bounds__(256) void cvt_f32_bf16(const float* __restrict__ src,
                                                    u16* __restrict__ dst) {
    const long i = ((long)blockIdx.x * 256 + threadIdx.x) * 8;
    f32x4 x0 = *(const f32x4*)(src + i);
    f32x4 x1 = *(const f32x4*)(src + i + 4);
    BF8 u;
#pragma unroll
    for (int j = 0; j < 4; ++j) {
        u.e[j] = (__bf16)x0[j];
        u.e[4 + j] = (__bf16)x1[j];
    }
    *(bf16x8*)(dst + i) = u.v;
}

// ---------------------------------------------------------------------------
// GEMM: Out[M=65536][768] = A[65536][768] * Bt^T + bias  (Bt is [N][K] bf16)
// 128x128 tile, BK=32, 256 threads. XOR-swizzled LDS (bank-conflict-free b128
// fragment reads, compatible with global_load_lds contiguous-dest rule).
//
// 2-phase pipeline (T3 minimum): double-buffered LDS; STAGE(next K-step) is
// issued BEFORE the ds_read+MFMA of the current buffer, so the compiler's
// vmcnt(0) drain at the (single) per-step __syncthreads lands after ~200
// cycles of compute — global latency hidden within each wave.
//
// XCD-aware block mapping (T1): bid = xcd + 8*local. All J n-blocks of one
// 128-row A panel get the SAME xcd and consecutive local slots, so the A
// panel is fetched into exactly one XCD's L2 (grids %8==0 -> bijective).
//
// FUSE: J=12, n-blocks 0..5 use {Bt0,bias0,Out0}, 6..11 use {Bt1,bias1,Out1}
// (fused K+V projection: the shared A = `values` is streamed from HBM once).
// ---------------------------------------------------------------------------
template <bool A_F32, bool OUT_F32, bool FUSE>
__global__ __launch_bounds__(256) void gemm_kernel(
    const void* __restrict__ Aptr,
    const u16* __restrict__ Bt0, const float* __restrict__ bias0, void* __restrict__ Out0,
    const u16* __restrict__ Bt1, const float* __restrict__ bias1, void* __restrict__ Out1) {
    constexpr int ABUF = A_F32 ? 16384 : 8192;  // bytes of A per buffer
    constexpr int BUF = ABUF + 8192;            // bytes per (A+B) buffer
    constexpr int J = FUSE ? 12 : 6;
    __shared__ __attribute__((aligned(16))) char smem[2 * BUF];

    const int bid = blockIdx.x;
    const int xcd = bid & 7;
    const int local = bid >> 3;
    const int j = local % J;
    const int mp = xcd * 64 + local / J;

    const bool first = !FUSE || (j < 6);
    const u16* Bt = first ? Bt0 : Bt1;
    const float* bias = first ? bias0 : bias1;
    void* Out = first ? Out0 : Out1;

    const int tid = threadIdx.x;
    const int wid = tid >> 6, lane = tid & 63;
    const int quad = lane >> 4, lm = lane & 15;
    const int mbase = (wid >> 1) * 64, nbase = (wid & 1) * 64;
    const long row0 = (long)mp * 128;
    const int n0 = (FUSE ? (j % 6) : j) * 128;

    auto stage = [&](int buf, int kt) {
        char* base = smem + buf * BUF;
        const int k0 = kt * 32;
        if constexpr (A_F32) {
            float* Asf = (float*)base;
            const float* A = (const float*)Aptr;
#pragma unroll
            for (int i = 0; i < 4; ++i) {
                int chunk = tid + 256 * i;  // 1024 chunks of 16B = 128x32 f32
                int m = chunk >> 3, s = chunk & 7;
                int kc = s ^ (m & 7);  // swizzled source column-chunk
                gld_lds16(A + (row0 + m) * 768 + k0 + kc * 4, Asf + chunk * 4);
            }
        } else {
            u16* Asb = (u16*)base;
            const u16* A = (const u16*)Aptr;
#pragma unroll
            for (int i = 0; i < 2; ++i) {
                int chunk = tid + 256 * i;  // 512 chunks = 128x32 bf16
                int m = chunk >> 2, s = chunk & 3;
                int kc = s ^ ((m >> 1) & 3);
                gld_lds16(A + (row0 + m) * 768 + k0 + kc * 8, Asb + chunk * 8);
            }
        }
        u16* Bs = (u16*)(base + ABUF);
#pragma unroll
        for (int i = 0; i < 2; ++i) {
            int chunk = tid + 256 * i;  // 512 chunks = 128(n) x 32(k) bf16
            int n = chunk >> 2, s = chunk & 3;
            int kc = s ^ ((n >> 1) & 3);
            gld_lds16(Bt + (long)(n0 + n) * 768 + k0 + kc * 8, Bs + chunk * 8);
        }
    };

    const f32x4 zero = {0.f, 0.f, 0.f, 0.f};
    f32x4 acc[4][4];
#pragma unroll
    for (int mi = 0; mi < 4; ++mi)
#pragma unroll
        for (int ni = 0; ni < 4; ++ni) acc[mi][ni] = zero;

    stage(0, 0);
    __syncthreads();  // drains vmcnt(0): buffer 0 ready

    int cur = 0;
    for (int kt = 0; kt < 24; ++kt) {
        if (kt < 23) stage(cur ^ 1, kt + 1);  // prefetch: issue EARLY

        char* base = smem + cur * BUF;
        float* Asf = (float*)base;
        u16* Asb = (u16*)base;
        u16* Bs = (u16*)(base + ABUF);

        bf16x8 af[4], bfr[4];
#pragma unroll
        for (int mi = 0; mi < 4; ++mi) {
            int m = mbase + mi * 16 + lm;
            if constexpr (A_F32) {
                int c0 = m * 8 + ((quad * 2) ^ (m & 7));
                int c1 = m * 8 + ((quad * 2 + 1) ^ (m & 7));
                f32x4 x0 = *(const f32x4*)(Asf + c0 * 4);
                f32x4 x1 = *(const f32x4*)(Asf + c1 * 4);
                BF8 u;
#pragma unroll
                for (int jj = 0; jj < 4; ++jj) {
                    u.e[jj] = (__bf16)x0[jj];
                    u.e[4 + jj] = (__bf16)x1[jj];
                }
                af[mi] = u.v;
            } else {
                int c = m * 4 + (quad ^ ((m >> 1) & 3));
                af[mi] = *(const bf16x8*)(Asb + c * 8);
            }
        }
#pragma unroll
        for (int ni = 0; ni < 4; ++ni) {
            int n = nbase + ni * 16 + lm;
            int c = n * 4 + (quad ^ ((n >> 1) & 3));
            bfr[ni] = *(const bf16x8*)(Bs + c * 8);
        }
#pragma unroll
        for (int mi = 0; mi < 4; ++mi)
#pragma unroll
            for (int ni = 0; ni < 4; ++ni)
                acc[mi][ni] = mfma16(af[mi], bfr[ni], acc[mi][ni]);

        __syncthreads();  // drains: prefetch landed + all reads of cur done
        cur ^= 1;
    }

    // epilogue: C/D layout row = quad*4+r, col = lane&15
#pragma unroll
    for (int mi = 0; mi < 4; ++mi) {
        const long row = row0 + mbase + mi * 16 + quad * 4;
#pragma unroll
        for (int ni = 0; ni < 4; ++ni) {
            const int n = n0 + nbase + ni * 16 + lm;
            const float bv = bias[n];
#pragma unroll
            for (int r = 0; r < 4; ++r) {
                float v = acc[mi][ni][r] + bv;
                if constexpr (OUT_F32)
                    ((float*)Out)[(row + r) * 768 + n] = v;
                else
                    ((u16*)Out)[(row + r) * 768 + n] = f2bf(v);
            }
        }
    }
}

// ---------------------------------------------------------------------------
// Axis attention: one block per (cross-pos, batch, head). head<6: attend along
// H; head>=6: along W. Seq 64, head dim 64. Q/K/V staged swizzled; V
// transposed in LDS (padded stride 72) so PV B-fragments are single b128s.
// ---------------------------------------------------------------------------
__global__ __launch_bounds__(256) void attn_kernel(const u16* __restrict__ q,
                                                   const u16* __restrict__ k,
                                                   const u16* __restrict__ v,
                                                   u16* __restrict__ o) {
    __shared__ __attribute__((aligned(16))) u16 Qs[64 * 64];
    __shared__ __attribute__((aligned(16))) u16 Ks[64 * 64];
    __shared__ __attribute__((aligned(16))) u16 Vs[64 * 64];
    __shared__ __attribute__((aligned(16))) u16 Vt[64 * 72];  // padded stride

    const int cross = blockIdx.x;
    const int b = blockIdx.y;
    const int head = blockIdx.z;
    const bool axis0 = head < 6;
    const int tid = threadIdx.x;
    const int wid = tid >> 6, lane = tid & 63;
    const int quad = lane >> 4, lm = lane & 15;

    const long base = (long)b * 4096 + (axis0 ? cross : cross * 64);
    const int pstride = axis0 ? 64 : 1;
    const int coloff = head * 64;

    // stage Q,K,V swizzled: slot(p, c) = p*8 + (c ^ (p&7)), 16B chunks
#pragma unroll
    for (int i = 0; i < 2; ++i) {
        int chunk = tid + 256 * i;  // 512 chunks = 64 pos x 8 chunks
        int p = chunk >> 3, s = chunk & 7;
        int c = s ^ (p & 7);
        long g = (base + (long)p * pstride) * 768 + coloff + c * 8;
        gld_lds16(q + g, Qs + chunk * 8);
        gld_lds16(k + g, Ks + chunk * 8);
        gld_lds16(v + g, Vs + chunk * 8);
    }
    __syncthreads();

    // transpose V: Vs[pos][d] (swizzled) -> Vt[d][pos] (stride 72)
#pragma unroll
    for (int i = 0; i < 2; ++i) {
        int chunk = tid + 256 * i;
        int pos = chunk & 63, cc = chunk >> 6;  // cc wave-uniform
        int slot = pos * 8 + (cc ^ (pos & 7));
        BF8 vv;
        vv.v = *(const bf16x8*)(Vs + slot * 8);
#pragma unroll
        for (int jj = 0; jj < 8; ++jj) Vt[(cc * 8 + jj) * 72 + pos] = vv.h[jj];
    }

    // S = Q K^T ; wave owns rows 16*wid..16*wid+15
    const f32x4 zero = {0.f, 0.f, 0.f, 0.f};
    f32x4 s[4];
#pragma unroll
    for (int nt = 0; nt < 4; ++nt) s[nt] = zero;

    bf16x8 qf[2];
#pragma unroll
    for (int kt = 0; kt < 2; ++kt) {
        int row = 16 * wid + lm;
        int slot = row * 8 + ((kt * 4 + quad) ^ (row & 7));
        qf[kt] = *(const bf16x8*)(Qs + slot * 8);
    }
#pragma unroll
    for (int nt = 0; nt < 4; ++nt)
#pragma unroll
        for (int kt = 0; kt < 2; ++kt) {
            int row = nt * 16 + lm;
            int slot = row * 8 + ((kt * 4 + quad) ^ (row & 7));
            bf16x8 kf = *(const bf16x8*)(Ks + slot * 8);
            s[nt] = mfma16(qf[kt], kf, s[nt]);
        }

    // softmax over 64 keys (rows h = 16*wid + quad*4 + r)
    float invl[4];
#pragma unroll
    for (int nt = 0; nt < 4; ++nt) s[nt] = s[nt] * 0.125f;  // 1/sqrt(64)
#pragma unroll
    for (int r = 0; r < 4; ++r) {
        float m = fmaxf(fmaxf(s[0][r], s[1][r]), fmaxf(s[2][r], s[3][r]));
#pragma unroll
        for (int d = 1; d < 16; d <<= 1) m = fmaxf(m, __shfl_xor(m, d));
        float l = 0.f;
#pragma unroll
        for (int nt = 0; nt < 4; ++nt) {
            float p = exp2f((s[nt][r] - m) * 1.44269504f);
            s[nt][r] = p;
            l += p;
        }
#pragma unroll
        for (int d = 1; d < 16; d <<= 1) l += __shfl_xor(l, d);
        invl[r] = 1.f / l;
    }

    // P (unnormalized bf16) -> Qs, same swizzled layout; wave writes only its
    // own 16 rows (the only Qs rows it reads), so no barrier needed here.
#pragma unroll
    for (int nt = 0; nt < 4; ++nt)
#pragma unroll
        for (int r = 0; r < 4; ++r) {
            int h = 16 * wid + quad * 4 + r;
            int c = nt * 2 + (lm >> 3);
            Qs[(h * 8 + (c ^ (h & 7))) * 8 + (lm & 7)] = f2bf(s[nt][r]);
        }
    __syncthreads();  // Vt ready (all waves) + P ready

    // O = P V ; B-fragment = single b128 from Vt
    f32x4 oacc[4];
#pragma unroll
    for (int nt = 0; nt < 4; ++nt) oacc[nt] = zero;
#pragma unroll
    for (int kt = 0; kt < 2; ++kt) {
        int row = 16 * wid + lm;
        int slot = row * 8 + ((kt * 4 + quad) ^ (row & 7));
        bf16x8 pf = *(const bf16x8*)(Qs + slot * 8);
#pragma unroll
        for (int nt = 0; nt < 4; ++nt) {
            bf16x8 vf = *(const bf16x8*)(Vt + (nt * 16 + lm) * 72 + kt * 32 + quad * 8);
            oacc[nt] = mfma16(pf, vf, oacc[nt]);
        }
    }

#pragma unroll
    for (int nt = 0; nt < 4; ++nt)
#pragma unroll
        for (int r = 0; r < 4; ++r) {
            int p = 16 * wid + quad * 4 + r;
            long grow = base + (long)p * pstride;
            o[grow * 768 + coloff + nt * 16 + lm] = f2bf(oacc[nt][r] * invl[r]);
        }
}

// ---------------------------------------------------------------------------
// ws layout (u16 units): q | k | v | attn (each 65536*768) | 4 x 768*768 wts
// aws doubles as values-bf16: cvt writes it, KV-GEMM reads it as A, then
// attn overwrites it (KV is complete by then).
// ---------------------------------------------------------------------------
extern "C" void kernel_launch(void* const* d_in, const int* in_sizes, int n_in,
                              void* d_out, int out_size, void* d_ws, size_t ws_size,
                              hipStream_t stream) {
    const float* queries = (const float*)d_in[0];
    const float* values = (const float*)d_in[1];
    const float* Wq = (const float*)d_in[2];
    const float* bq = (const float*)d_in[3];
    const float* Wk = (const float*)d_in[4];
    const float* bk = (const float*)d_in[5];
    const float* Wv = (const float*)d_in[6];
    const float* bv = (const float*)d_in[7];
    const float* Wo = (const float*)d_in[8];
    const float* bo = (const float*)d_in[9];

    const long MAT = 65536L * 768;
    const long WMAT = 768L * 768;
    u16* qws = (u16*)d_ws;
    u16* kws = qws + MAT;
    u16* vws = kws + MAT;
    u16* aws = vws + MAT;
    u16* wtq = aws + MAT;
    u16* wtk = wtq + WMAT;
    u16* wtv = wtk + WMAT;
    u16* wto = wtv + WMAT;

    dim3 tb(256);
    dim3 tg(12, 12);
    transpose_cvt<<<tg, tb, 0, stream>>>(Wq, wtq);
    transpose_cvt<<<tg, tb, 0, stream>>>(Wk, wtk);
    transpose_cvt<<<tg, tb, 0, stream>>>(Wv, wtv);
    transpose_cvt<<<tg, tb, 0, stream>>>(Wo, wto);

    // values f32 -> bf16 into aws (50331648 elems / 8 per thread / 256)
    cvt_f32_bf16<<<dim3(24576), tb, 0, stream>>>(values, aws);

    // 512 m-panels x J n-blocks, XCD-swizzled inside the kernel (grids %8==0)
    gemm_kernel<true, false, false><<<dim3(512 * 6), tb, 0, stream>>>(
        queries, wtq, bq, qws, nullptr, nullptr, nullptr);
    gemm_kernel<false, false, true><<<dim3(512 * 12), tb, 0, stream>>>(
        aws, wtk, bk, kws, wtv, bv, vws);

    attn_kernel<<<dim3(64, 16, 12), tb, 0, stream>>>(qws, kws, vws, aws);

    gemm_kernel<false, true, false><<<dim3(512 * 6), tb, 0, stream>>>(
        aws, wto, bo, (float*)d_out, nullptr, nullptr, nullptr);
}

// Round 3
// 965.027 us; speedup vs baseline: 1.1799x; 1.0147x over previous
//
#include <hip/hip_runtime.h>

typedef unsigned short u16;
typedef __bf16 bf16x8 __attribute__((ext_vector_type(8)));
typedef float f32x4 __attribute__((ext_vector_type(4)));

union BF8 {
    bf16x8 v;
    __bf16 e[8];
    u16 h[8];
};

typedef __attribute__((address_space(1))) void gvoid;
typedef __attribute__((address_space(3))) void lvoid;

__device__ __forceinline__ u16 f2bf(float f) {
    __bf16 h = (__bf16)f;
    return __builtin_bit_cast(u16, h);
}

// async global->LDS, 16B per lane; LDS dest must be wave-uniform base + lane*16
__device__ __forceinline__ void gld_lds16(const void* g, void* l) {
    __builtin_amdgcn_global_load_lds((gvoid*)g, (lvoid*)l, 16, 0, 0);
}

__device__ __forceinline__ f32x4 mfma16(bf16x8 a, bf16x8 b, f32x4 c) {
    return __builtin_amdgcn_mfma_f32_16x16x32_bf16(a, b, c, 0, 0, 0);
}

// ---------------------------------------------------------------------------
// Transpose 768x768 f32 -> bf16 (dst[n][k] = src[k][n])
// ---------------------------------------------------------------------------
__global__ __launch_bounds__(256) void transpose_cvt(const float* __restrict__ src,
                                                     u16* __restrict__ dst) {
    __shared__ float t[64][65];
    const int c0 = blockIdx.x * 64, r0 = blockIdx.y * 64;
    const int tid = threadIdx.x;
#pragma unroll
    for (int i = 0; i < 16; ++i) {
        int e = tid + 256 * i;
        int rr = e >> 6, cc = e & 63;
        t[rr][cc] = src[(r0 + rr) * 768 + c0 + cc];
    }
    __syncthreads();
#pragma unroll
    for (int i = 0; i < 16; ++i) {
        int e = tid + 256 * i;
        int rr = e >> 6, cc = e & 63;
        dst[(c0 + rr) * 768 + r0 + cc] = f2bf(t[cc][rr]);
    }
}

// ---------------------------------------------------------------------------
// Elementwise f32 -> bf16 (vectorized, 8 elems/thread).
// ---------------------------------------------------------------------------
__global__ __launch_bounds__(256) void cvt_f32_bf16(const float* __restrict__ src,
                                                    u16* __restrict__ dst) {
    const long i = ((long)blockIdx.x * 256 + threadIdx.x) * 8;
    f32x4 x0 = *(const f32x4*)(src + i);
    f32x4 x1 = *(const f32x4*)(src + i + 4);
    BF8 u;
#pragma unroll
    for (int j = 0; j < 4; ++j) {
        u.e[j] = (__bf16)x0[j];
        u.e[4 + j] = (__bf16)x1[j];
    }
    *(bf16x8*)(dst + i) = u.v;
}

// ---------------------------------------------------------------------------
// Deep-pipelined GEMM: Out[65536][768(*2)] = A[65536][768]*Bt^T + bias.
// A is bf16 (pre-converted). 256x256 tile, BK=32, 512 threads = 8 waves
// (2M x 4N), wave tile 128x64, acc[8][4], 32 MFMA / K-step.
//
// LDS: 4-slot ring x (A 16KB + B 16KB) = 128KB. Stage tile t+3 while
// computing tile t (2 tiles always in flight). Raw s_barrier + counted
// s_waitcnt vmcnt(8) (never 0 mid-loop) => no per-step vmcnt(0) drain (T4).
// lgkmcnt(0)+sched_barrier(0) fences MFMA from its ds_reads (rule #18).
// s_setprio(1) around the MFMA cluster (T5). XOR-swizzled LDS (T2).
//
// Safety: stage(t+3) targets buf[(t-1)%4], whose ds_reads were delivered
// before step t-1's closing barrier; tile t+1 is certified by vmcnt(8) +
// barrier at the end of step t before step t+1 reads it. All control flow
// wave-uniform (no deadlock).
//
// XCD mapping (T1): xcd = bid&7, local = bid>>3; j = local%J selects the
// n-block (and output for FUSE), mp = xcd*32 + local/J. Grids %8==0.
// ---------------------------------------------------------------------------
template <bool OUT_F32, bool FUSE>
__global__ __launch_bounds__(512, 2) void gemm256(
    const u16* __restrict__ Abf,
    const u16* __restrict__ Bt0, const float* __restrict__ bias0, void* __restrict__ Out0,
    const u16* __restrict__ Bt1, const float* __restrict__ bias1, void* __restrict__ Out1) {
    constexpr int J = FUSE ? 6 : 3;
    constexpr int NT = 24;  // K-tiles of 32
    __shared__ __attribute__((aligned(16))) char smem[4 * 32768];

    const int bid = blockIdx.x;
    const int xcd = bid & 7;
    const int local = bid >> 3;
    const int j = local % J;
    const int mp = xcd * 32 + local / J;

    const bool first = !FUSE || (j < 3);
    const u16* Bt = first ? Bt0 : Bt1;
    const float* bias = first ? bias0 : bias1;
    void* Out = first ? Out0 : Out1;

    const int tid = threadIdx.x;
    const int wid = tid >> 6, lane = tid & 63;
    const int quad = lane >> 4, lm = lane & 15;
    const int wm = wid >> 2, wn = wid & 3;
    const long row0 = (long)mp * 256;
    const int n0 = (FUSE ? (j % 3) : j) * 256;

    // per-thread staging source precompute: chunks tid and tid+512 of the
    // 1024-chunk (256 rows x 4 slots) tile; dest slot = src col-chunk XOR'd.
    const int ch0 = tid, ch1 = tid + 512;
    const int ar0 = ch0 >> 2, as0 = (ch0 & 3) ^ ((ar0 >> 1) & 3);
    const int ar1 = ch1 >> 2, as1 = (ch1 & 3) ^ ((ar1 >> 1) & 3);
    const u16* aSrc0 = Abf + (row0 + ar0) * 768 + as0 * 8;
    const u16* aSrc1 = Abf + (row0 + ar1) * 768 + as1 * 8;
    const u16* bSrc0 = Bt + (long)(n0 + ar0) * 768 + as0 * 8;
    const u16* bSrc1 = Bt + (long)(n0 + ar1) * 768 + as1 * 8;

    auto stage = [&](int t) {
        char* base = smem + (t & 3) * 32768;
        u16* As = (u16*)base;
        u16* Bs = (u16*)(base + 16384);
        const int k0 = t * 32;
        gld_lds16(aSrc0 + k0, As + ch0 * 8);
        gld_lds16(aSrc1 + k0, As + ch1 * 8);
        gld_lds16(bSrc0 + k0, Bs + ch0 * 8);
        gld_lds16(bSrc1 + k0, Bs + ch1 * 8);
    };

    bf16x8 af[8], bfr[4];
    auto frag_read = [&](int t) {
        const u16* As = (const u16*)(smem + (t & 3) * 32768);
        const u16* Bs = As + 8192;
#pragma unroll
        for (int mi = 0; mi < 8; ++mi) {
            int row = wm * 128 + mi * 16 + lm;
            int c = row * 4 + (quad ^ ((row >> 1) & 3));
            af[mi] = *(const bf16x8*)(As + c * 8);
        }
#pragma unroll
        for (int ni = 0; ni < 4; ++ni) {
            int row = wn * 64 + ni * 16 + lm;
            int c = row * 4 + (quad ^ ((row >> 1) & 3));
            bfr[ni] = *(const bf16x8*)(Bs + c * 8);
        }
    };

    const f32x4 zero = {0.f, 0.f, 0.f, 0.f};
    f32x4 acc[8][4];
#pragma unroll
    for (int mi = 0; mi < 8; ++mi)
#pragma unroll
        for (int ni = 0; ni < 4; ++ni) acc[mi][ni] = zero;

    auto mfma_cluster = [&]() {
        __builtin_amdgcn_s_setprio(1);
#pragma unroll
        for (int mi = 0; mi < 8; ++mi)
#pragma unroll
            for (int ni = 0; ni < 4; ++ni)
                acc[mi][ni] = mfma16(af[mi], bfr[ni], acc[mi][ni]);
        __builtin_amdgcn_s_setprio(0);
    };

    // prologue: stage tiles 0,1,2; certify tile 0 (vmcnt: 8 newer remain)
    stage(0);
    stage(1);
    stage(2);
    asm volatile("s_waitcnt vmcnt(8)" ::: "memory");
    __builtin_amdgcn_sched_barrier(0);
    __builtin_amdgcn_s_barrier();

    for (int t = 0; t < 21; ++t) {
        frag_read(t);
        stage(t + 3);  // into buf[(t-1)%4], released at end of step t-1
        __builtin_amdgcn_s_barrier();
        asm volatile("s_waitcnt lgkmcnt(0)" ::: "memory");
        __builtin_amdgcn_sched_barrier(0);
        mfma_cluster();
        asm volatile("s_waitcnt vmcnt(8)" ::: "memory");  // certify tile t+1
        __builtin_amdgcn_sched_barrier(0);
        __builtin_amdgcn_s_barrier();
    }
    // t = 21 (tiles 22,23 outstanding after certify -> vmcnt(4))
    frag_read(21);
    __builtin_amdgcn_s_barrier();
    asm volatile("s_waitcnt lgkmcnt(0)" ::: "memory");
    __builtin_amdgcn_sched_barrier(0);
    mfma_cluster();
    asm volatile("s_waitcnt vmcnt(4)" ::: "memory");
    __builtin_amdgcn_sched_barrier(0);
    __builtin_amdgcn_s_barrier();
    // t = 22 (certify tile 23)
    frag_read(22);
    __builtin_amdgcn_s_barrier();
    asm volatile("s_waitcnt lgkmcnt(0)" ::: "memory");
    __builtin_amdgcn_sched_barrier(0);
    mfma_cluster();
    asm volatile("s_waitcnt vmcnt(0)" ::: "memory");
    __builtin_amdgcn_sched_barrier(0);
    __builtin_amdgcn_s_barrier();
    // t = 23 (last)
    frag_read(23);
    asm volatile("s_waitcnt lgkmcnt(0)" ::: "memory");
    __builtin_amdgcn_sched_barrier(0);
    mfma_cluster();

    // epilogue: C/D layout row = quad*4+r, col = lane&15
#pragma unroll
    for (int mi = 0; mi < 8; ++mi) {
        const long row = row0 + wm * 128 + mi * 16 + quad * 4;
#pragma unroll
        for (int ni = 0; ni < 4; ++ni) {
            const int n = n0 + wn * 64 + ni * 16 + lm;
            const float bv = bias[n];
#pragma unroll
            for (int r = 0; r < 4; ++r) {
                float v = acc[mi][ni][r] + bv;
                if constexpr (OUT_F32)
                    ((float*)Out)[(row + r) * 768 + n] = v;
                else
                    ((u16*)Out)[(row + r) * 768 + n] = f2bf(v);
            }
        }
    }
}

// ---------------------------------------------------------------------------
// Axis attention: one block per (cross-pos, batch, head). head<6: attend along
// H; head>=6: along W. Seq 64, head dim 64. Q/K/V staged swizzled; V
// transposed in LDS (padded stride 72) so PV B-fragments are single b128s.
// ---------------------------------------------------------------------------
__global__ __launch_bounds__(256) void attn_kernel(const u16* __restrict__ q,
                                                   const u16* __restrict__ k,
                                                   const u16* __restrict__ v,
                                                   u16* __restrict__ o) {
    __shared__ __attribute__((aligned(16))) u16 Qs[64 * 64];
    __shared__ __attribute__((aligned(16))) u16 Ks[64 * 64];
    __shared__ __attribute__((aligned(16))) u16 Vs[64 * 64];
    __shared__ __attribute__((aligned(16))) u16 Vt[64 * 72];  // padded stride

    const int cross = blockIdx.x;
    const int b = blockIdx.y;
    const int head = blockIdx.z;
    const bool axis0 = head < 6;
    const int tid = threadIdx.x;
    const int wid = tid >> 6, lane = tid & 63;
    const int quad = lane >> 4, lm = lane & 15;

    const long base = (long)b * 4096 + (axis0 ? cross : cross * 64);
    const int pstride = axis0 ? 64 : 1;
    const int coloff = head * 64;

    // stage Q,K,V swizzled: slot(p, c) = p*8 + (c ^ (p&7)), 16B chunks
#pragma unroll
    for (int i = 0; i < 2; ++i) {
        int chunk = tid + 256 * i;  // 512 chunks = 64 pos x 8 chunks
        int p = chunk >> 3, s = chunk & 7;
        int c = s ^ (p & 7);
        long g = (base + (long)p * pstride) * 768 + coloff + c * 8;
        gld_lds16(q + g, Qs + chunk * 8);
        gld_lds16(k + g, Ks + chunk * 8);
        gld_lds16(v + g, Vs + chunk * 8);
    }
    __syncthreads();

    // transpose V: Vs[pos][d] (swizzled) -> Vt[d][pos] (stride 72)
#pragma unroll
    for (int i = 0; i < 2; ++i) {
        int chunk = tid + 256 * i;
        int pos = chunk & 63, cc = chunk >> 6;  // cc wave-uniform
        int slot = pos * 8 + (cc ^ (pos & 7));
        BF8 vv;
        vv.v = *(const bf16x8*)(Vs + slot * 8);
#pragma unroll
        for (int jj = 0; jj < 8; ++jj) Vt[(cc * 8 + jj) * 72 + pos] = vv.h[jj];
    }

    // S = Q K^T ; wave owns rows 16*wid..16*wid+15
    const f32x4 zero = {0.f, 0.f, 0.f, 0.f};
    f32x4 s[4];
#pragma unroll
    for (int nt = 0; nt < 4; ++nt) s[nt] = zero;

    bf16x8 qf[2];
#pragma unroll
    for (int kt = 0; kt < 2; ++kt) {
        int row = 16 * wid + lm;
        int slot = row * 8 + ((kt * 4 + quad) ^ (row & 7));
        qf[kt] = *(const bf16x8*)(Qs + slot * 8);
    }
#pragma unroll
    for (int nt = 0; nt < 4; ++nt)
#pragma unroll
        for (int kt = 0; kt < 2; ++kt) {
            int row = nt * 16 + lm;
            int slot = row * 8 + ((kt * 4 + quad) ^ (row & 7));
            bf16x8 kf = *(const bf16x8*)(Ks + slot * 8);
            s[nt] = mfma16(qf[kt], kf, s[nt]);
        }

    // softmax over 64 keys (rows h = 16*wid + quad*4 + r)
    float invl[4];
#pragma unroll
    for (int nt = 0; nt < 4; ++nt) s[nt] = s[nt] * 0.125f;  // 1/sqrt(64)
#pragma unroll
    for (int r = 0; r < 4; ++r) {
        float m = fmaxf(fmaxf(s[0][r], s[1][r]), fmaxf(s[2][r], s[3][r]));
#pragma unroll
        for (int d = 1; d < 16; d <<= 1) m = fmaxf(m, __shfl_xor(m, d));
        float l = 0.f;
#pragma unroll
        for (int nt = 0; nt < 4; ++nt) {
            float p = exp2f((s[nt][r] - m) * 1.44269504f);
            s[nt][r] = p;
            l += p;
        }
#pragma unroll
        for (int d = 1; d < 16; d <<= 1) l += __shfl_xor(l, d);
        invl[r] = 1.f / l;
    }

    // P (unnormalized bf16) -> Qs, same swizzled layout; wave writes only its
    // own 16 rows (the only Qs rows it reads), so no barrier needed here.
#pragma unroll
    for (int nt = 0; nt < 4; ++nt)
#pragma unroll
        for (int r = 0; r < 4; ++r) {
            int h = 16 * wid + quad * 4 + r;
            int c = nt * 2 + (lm >> 3);
            Qs[(h * 8 + (c ^ (h & 7))) * 8 + (lm & 7)] = f2bf(s[nt][r]);
        }
    __syncthreads();  // Vt ready (all waves) + P ready

    // O = P V ; B-fragment = single b128 from Vt
    f32x4 oacc[4];
#pragma unroll
    for (int nt = 0; nt < 4; ++nt) oacc[nt] = zero;
#pragma unroll
    for (int kt = 0; kt < 2; ++kt) {
        int row = 16 * wid + lm;
        int slot = row * 8 + ((kt * 4 + quad) ^ (row & 7));
        bf16x8 pf = *(const bf16x8*)(Qs + slot * 8);
#pragma unroll
        for (int nt = 0; nt < 4; ++nt) {
            bf16x8 vf = *(const bf16x8*)(Vt + (nt * 16 + lm) * 72 + kt * 32 + quad * 8);
            oacc[nt] = mfma16(pf, vf, oacc[nt]);
        }
    }

#pragma unroll
    for (int nt = 0; nt < 4; ++nt)
#pragma unroll
        for (int r = 0; r < 4; ++r) {
            int p = 16 * wid + quad * 4 + r;
            long grow = base + (long)p * pstride;
            o[grow * 768 + coloff + nt * 16 + lm] = f2bf(oacc[nt][r] * invl[r]);
        }
}

// ---------------------------------------------------------------------------
// ws layout (u16 units): q | k | v | attn (each 65536*768) | 4 x 768*768 wts
// aws is time-shared: queries-bf16 (q-GEMM A) -> values-bf16 (KV-GEMM A) ->
// attn output (out-GEMM A). Stream order makes each handoff safe.
// ---------------------------------------------------------------------------
extern "C" void kernel_launch(void* const* d_in, const int* in_sizes, int n_in,
                              void* d_out, int out_size, void* d_ws, size_t ws_size,
                              hipStream_t stream) {
    const float* queries = (const float*)d_in[0];
    const float* values = (const float*)d_in[1];
    const float* Wq = (const float*)d_in[2];
    const float* bq = (const float*)d_in[3];
    const float* Wk = (const float*)d_in[4];
    const float* bk = (const float*)d_in[5];
    const float* Wv = (const float*)d_in[6];
    const float* bv = (const float*)d_in[7];
    const float* Wo = (const float*)d_in[8];
    const float* bo = (const float*)d_in[9];

    const long MAT = 65536L * 768;
    const long WMAT = 768L * 768;
    u16* qws = (u16*)d_ws;
    u16* kws = qws + MAT;
    u16* vws = kws + MAT;
    u16* aws = vws + MAT;
    u16* wtq = aws + MAT;
    u16* wtk = wtq + WMAT;
    u16* wtv = wtk + WMAT;
    u16* wto = wtv + WMAT;

    dim3 tb(256);
    dim3 tg(12, 12);
    transpose_cvt<<<tg, tb, 0, stream>>>(Wq, wtq);
    transpose_cvt<<<tg, tb, 0, stream>>>(Wk, wtk);
    transpose_cvt<<<tg, tb, 0, stream>>>(Wv, wtv);
    transpose_cvt<<<tg, tb, 0, stream>>>(Wo, wto);

    dim3 tb5(512);
    // queries f32 -> bf16 into aws; q-GEMM consumes it
    cvt_f32_bf16<<<dim3(24576), tb, 0, stream>>>(queries, aws);
    gemm256<false, false><<<dim3(768), tb5, 0, stream>>>(
        aws, wtq, bq, qws, nullptr, nullptr, nullptr);

    // values f32 -> bf16 into aws (q-GEMM done with it); fused K+V GEMM
    cvt_f32_bf16<<<dim3(24576), tb, 0, stream>>>(values, aws);
    gemm256<false, true><<<dim3(1536), tb5, 0, stream>>>(
        aws, wtk, bk, kws, wtv, bv, vws);

    attn_kernel<<<dim3(64, 16, 12), tb, 0, stream>>>(qws, kws, vws, aws);

    gemm256<true, false><<<dim3(768), tb5, 0, stream>>>(
        aws, wto, bo, (float*)d_out, nullptr, nullptr, nullptr);
}